// Round 1
// baseline (658.788 us; speedup 1.0000x reference)
//
#include <hip/hip_runtime.h>
#include <hip/hip_bf16.h>

#define BB   2
#define NN   128
#define SS   4
#define DGG  8
#define CIN  4
#define COUT 8
#define HH   32

typedef __attribute__((ext_vector_type(4))) float          fvec4;
typedef __attribute__((ext_vector_type(4))) unsigned short usvec4;
typedef __attribute__((ext_vector_type(8))) unsigned short usvec8;

// LDS layout (float offsets)
#define O_YW1  0      // ky_W1: 4*32*2   = 256
#define O_YB1  256    // ky_b1: 4*32     = 128
#define O_YW2  384    // ky_W2: 4*32*32  = 4096
#define O_YB2  4480   // ky_b2: 128
#define O_YW3  4608   // ky_W3: 128
#define O_YB3  4736   // ky_b3: 4
#define O_GW1  4740   // kg_W1: 4*32*8   = 1024
#define O_GB1  5764   // kg_b1: 128
#define O_GW2  5892   // kg_W2: 4096
#define O_GB2  9988   // kg_b2: 128
#define O_GW3  10116  // kg_W3: 128
#define O_GB3  10244  // kg_b3: 4
#define O_WOUT 10248  // w_out: 32
#define W_TOTAL 10280
#define O_PART  W_TOTAL          // 8 waves * 4 s1 * 8 = 256
#define O_ACCF  (W_TOTAL + 256)  // 32
#define O_CF    (W_TOTAL + 288)  // 16
#define SM_TOTAL (W_TOTAL + 304)

__device__ __forceinline__ float bf2f(unsigned short u) {
    return __uint_as_float(((unsigned int)u) << 16);
}

__device__ __forceinline__ float silu_f(float x) {
    // x * sigmoid(x); v_rcp_f32 approx is ~1ulp, fine vs 2% threshold
    return x * __builtin_amdgcn_rcpf(1.0f + __expf(-x));
}

// ---- dtype detection (deterministic per input, graph-capture safe) ----
// modes[0]: 0 = float tensors are f32, 1 = bf16
// modes[1]: mask dtype: 0=i32, 1=bf16, 2=u8/bool, 3=f32
__global__ void detect_kernel(const void* maskp, const void* cosetp, int* modes) {
    int lane = threadIdx.x;  // 64 threads
    // Float dtype: look at even u16 words of coset_functions (N(0,1) values).
    // bf16 -> word is a bf16 pattern with exponent in ~[110,135]; f32 -> word
    // is low mantissa bits (uniform) -> ~10% hit rate.  256B read: safe.
    const unsigned short* cu = (const unsigned short*)cosetp;
    unsigned short v = cu[2 * lane];
    int e = (v >> 7) & 0xFF;
    int hit = (e >= 110 && e <= 135) ? 1 : 0;
    int hits = __popcll(__ballot(hit));
    int fmode = (hits > 32) ? 1 : 0;

    // Mask dtype from bit patterns over first 1024 bytes (safe for all widths)
    const unsigned short* mu = (const unsigned short*)maskp;
    int evenBF = 0, any3 = 0, anyByte = 0;
    for (int r = 0; r < 8; ++r) {
        int idx = lane + r * 64;
        unsigned short m = mu[idx];
        if (m == 0x3F80) { any3 = 1; if (!(idx & 1)) evenBF = 1; }
        if (m == 0x0101 || m == 0x0100) anyByte = 1;
    }
    evenBF  = (__ballot(evenBF)  != 0ull);
    any3    = (__ballot(any3)    != 0ull);
    anyByte = (__ballot(anyByte) != 0ull);
    if (lane == 0) {
        modes[0] = fmode;
        modes[1] = evenBF ? 1 : (any3 ? 3 : (anyByte ? 2 : 0));
    }
}

__device__ __forceinline__ void copy_arr(float* sm, const void* src, int off,
                                         int cnt, int fmode, int tid) {
    if (fmode) {
        const unsigned short* s = (const unsigned short*)src;
        for (int x = tid; x < cnt; x += 512) sm[off + x] = bf2f(s[x]);
    } else {
        const float* s = (const float*)src;
        for (int x = tid; x < cnt; x += 512) sm[off + x] = s[x];
    }
}

__device__ __forceinline__ void load4(const void* p, int base, int fmode, float* dst) {
    if (fmode) {
        usvec4 v = *(const usvec4*)((const unsigned short*)p + base);
        dst[0] = bf2f(v[0]); dst[1] = bf2f(v[1]);
        dst[2] = bf2f(v[2]); dst[3] = bf2f(v[3]);
    } else {
        fvec4 v = *(const fvec4*)((const float*)p + base);
        dst[0] = v[0]; dst[1] = v[1]; dst[2] = v[2]; dst[3] = v[3];
    }
}

__device__ __forceinline__ void load8(const void* p, int base, int fmode, float* dst) {
    if (fmode) {
        usvec8 v = *(const usvec8*)((const unsigned short*)p + base);
#pragma unroll
        for (int d = 0; d < 8; ++d) dst[d] = bf2f(v[d]);
    } else {
        fvec4 a = *(const fvec4*)((const float*)p + base);
        fvec4 b = *(const fvec4*)((const float*)p + base + 4);
        dst[0] = a[0]; dst[1] = a[1]; dst[2] = a[2]; dst[3] = a[3];
        dst[4] = b[0]; dst[5] = b[1]; dst[6] = b[2]; dst[7] = b[3];
    }
}

__device__ __forceinline__ int load_mask(const void* p, int idx, int mmode) {
    if (mmode == 0) return ((const int*)p)[idx] != 0;
    if (mmode == 1) return ((const unsigned short*)p)[idx] != 0;
    if (mmode == 2) return ((const unsigned char*)p)[idx] != 0;
    return ((const unsigned int*)p)[idx] != 0;
}

// One block per (b, n1). 512 threads: t = n2b*16 + s1*4 + s2, n2b in [0,32).
// Each thread covers n2 = n2b + {0,32,64,96} as 2 pairs (P=2 position batching
// so each ds_read_b128 of weights feeds >=8 FMAs -> VALU-bound, not LDS-bound).
__global__ __launch_bounds__(512, 2) void emha_kernel(
    const void* g_pw, const void* g_coset, const void* g_mask,
    const void* yW1, const void* yb1, const void* yW2, const void* yb2,
    const void* yW3, const void* yb3,
    const void* gW1, const void* gb1, const void* gW2, const void* gb2,
    const void* gW3, const void* gb3,
    const void* wout, const int* modes, void* outp)
{
    __shared__ float sm[SM_TOTAL];
    const int tid = threadIdx.x;
    const int fmode = modes[0];
    const int mmode = modes[1];
    const int blk = blockIdx.x;
    const int b  = blk >> 7;
    const int n1 = blk & 127;

    copy_arr(sm, yW1, O_YW1, 256,  fmode, tid);
    copy_arr(sm, yb1, O_YB1, 128,  fmode, tid);
    copy_arr(sm, yW2, O_YW2, 4096, fmode, tid);
    copy_arr(sm, yb2, O_YB2, 128,  fmode, tid);
    copy_arr(sm, yW3, O_YW3, 128,  fmode, tid);
    copy_arr(sm, yb3, O_YB3, 4,    fmode, tid);
    copy_arr(sm, gW1, O_GW1, 1024, fmode, tid);
    copy_arr(sm, gb1, O_GB1, 128,  fmode, tid);
    copy_arr(sm, gW2, O_GW2, 4096, fmode, tid);
    copy_arr(sm, gb2, O_GB2, 128,  fmode, tid);
    copy_arr(sm, gW3, O_GW3, 128,  fmode, tid);
    copy_arr(sm, gb3, O_GB3, 4,    fmode, tid);
    copy_arr(sm, wout, O_WOUT, 32, fmode, tid);
    __syncthreads();

    const int s2  = tid & 3;
    const int s1  = (tid >> 2) & 3;
    const int n2b = tid >> 4;

    float fb[4];
    load4(g_coset, ((b * NN + n1) * SS + s1) * CIN, fmode, fb);

    float accN[4] = {0.f, 0.f, 0.f, 0.f};
    float accD[4] = {0.f, 0.f, 0.f, 0.f};

#pragma unroll 1
    for (int pair = 0; pair < 2; ++pair) {
        const int n2A = n2b + (pair * 2 + 0) * 32;
        const int n2B = n2b + (pair * 2 + 1) * 32;
        float gA[8], gB[8], faA[4], faB[4];
        const int posA = (((b * NN + n1) * NN + n2A) * SS + s1) * SS + s2;
        const int posB = (((b * NN + n1) * NN + n2B) * SS + s1) * SS + s2;
        load8(g_pw, posA * DGG, fmode, gA);
        load8(g_pw, posB * DGG, fmode, gB);
        load4(g_coset, ((b * NN + n2A) * SS + s2) * CIN, fmode, faA);
        load4(g_coset, ((b * NN + n2B) * SS + s2) * CIN, fmode, faB);
        const int mA = load_mask(g_mask, (b * NN + n2A) * SS + s2, mmode);
        const int mB = load_mask(g_mask, (b * NN + n2B) * SS + s2, mmode);

#pragma unroll
        for (int i = 0; i < CIN; ++i) {
            float h1[2][HH], h2[2][HH];
            // ---- ky MLP ----
            {
                const float* W1 = &sm[O_YW1 + i * 64];
                const float* B1 = &sm[O_YB1 + i * HH];
#pragma unroll 8
                for (int j = 0; j < HH; ++j) {
                    float w0 = W1[j * 2], w1 = W1[j * 2 + 1], bb = B1[j];
                    float c = w1 * fb[i] + bb;
                    h1[0][j] = silu_f(w0 * faA[i] + c);
                    h1[1][j] = silu_f(w0 * faB[i] + c);
                }
                const float* W2 = &sm[O_YW2 + i * 1024];
                const float* B2 = &sm[O_YB2 + i * HH];
#pragma unroll 4
                for (int j = 0; j < HH; ++j) {
                    float d0 = 0.f, d1 = 0.f;
#pragma unroll
                    for (int k = 0; k < HH; ++k) {
                        float w = W2[j * HH + k];
                        d0 += w * h1[0][k];
                        d1 += w * h1[1][k];
                    }
                    float bb = B2[j];
                    h2[0][j] = silu_f(d0 + bb);
                    h2[1][j] = silu_f(d1 + bb);
                }
            }
            float ky0, ky1;
            {
                const float* W3 = &sm[O_YW3 + i * HH];
                float d0 = 0.f, d1 = 0.f;
#pragma unroll
                for (int k = 0; k < HH; ++k) {
                    float w = W3[k];
                    d0 += w * h2[0][k];
                    d1 += w * h2[1][k];
                }
                float bb = sm[O_YB3 + i];
                ky0 = silu_f(d0 + bb);
                ky1 = silu_f(d1 + bb);
            }
            // ---- kg MLP ----
            {
                const float* W1 = &sm[O_GW1 + i * 256];
                const float* B1 = &sm[O_GB1 + i * HH];
#pragma unroll 4
                for (int j = 0; j < HH; ++j) {
                    float d0 = B1[j], d1 = B1[j];
#pragma unroll
                    for (int d = 0; d < DGG; ++d) {
                        float w = W1[j * DGG + d];
                        d0 += w * gA[d];
                        d1 += w * gB[d];
                    }
                    h1[0][j] = silu_f(d0);
                    h1[1][j] = silu_f(d1);
                }
                const float* W2 = &sm[O_GW2 + i * 1024];
                const float* B2 = &sm[O_GB2 + i * HH];
#pragma unroll 4
                for (int j = 0; j < HH; ++j) {
                    float d0 = 0.f, d1 = 0.f;
#pragma unroll
                    for (int k = 0; k < HH; ++k) {
                        float w = W2[j * HH + k];
                        d0 += w * h1[0][k];
                        d1 += w * h1[1][k];
                    }
                    float bb = B2[j];
                    h2[0][j] = silu_f(d0 + bb);
                    h2[1][j] = silu_f(d1 + bb);
                }
            }
            float kg0, kg1;
            {
                const float* W3 = &sm[O_GW3 + i * HH];
                float d0 = 0.f, d1 = 0.f;
#pragma unroll
                for (int k = 0; k < HH; ++k) {
                    float w = W3[k];
                    d0 += w * h2[0][k];
                    d1 += w * h2[1][k];
                }
                float bb = sm[O_GB3 + i];
                kg0 = silu_f(d0 + bb);
                kg1 = silu_f(d1 + bb);
            }
            float e0 = mA ? __expf(ky0 + kg0) : 0.f;
            float e1 = mB ? __expf(ky1 + kg1) : 0.f;
            accD[i] += e0 + e1;
            accN[i] += e0 * faA[i] + e1 * faB[i];
        }
    }

    // Reduce over s2 (lane bits 0,1) and n2b-low (lane bits 4,5)
#pragma unroll
    for (int i = 0; i < CIN; ++i) {
        accN[i] += __shfl_xor(accN[i], 1);
        accD[i] += __shfl_xor(accD[i], 1);
        accN[i] += __shfl_xor(accN[i], 2);
        accD[i] += __shfl_xor(accD[i], 2);
        accN[i] += __shfl_xor(accN[i], 16);
        accD[i] += __shfl_xor(accD[i], 16);
        accN[i] += __shfl_xor(accN[i], 32);
        accD[i] += __shfl_xor(accD[i], 32);
    }
    const int lane = tid & 63;
    const int wave = tid >> 6;
    if ((lane & 51) == 0) {  // lanes 0,4,8,12: holders per s1
        const int ps1 = (lane >> 2) & 3;
        float* p = &sm[O_PART + (wave * 4 + ps1) * 8];
#pragma unroll
        for (int i = 0; i < CIN; ++i) {
            p[i * 2]     = accN[i];
            p[i * 2 + 1] = accD[i];
        }
    }
    __syncthreads();
    if (tid < 32) {
        const int ps1 = tid >> 3, j = tid & 7;
        float v = 0.f;
#pragma unroll
        for (int w = 0; w < 8; ++w) v += sm[O_PART + (w * 4 + ps1) * 8 + j];
        sm[O_ACCF + ps1 * 8 + j] = v;
    }
    __syncthreads();
    if (tid < 16) {
        const int ps1 = tid >> 2, i = tid & 3;
        float num = sm[O_ACCF + ps1 * 8 + i * 2];
        float den = sm[O_ACCF + ps1 * 8 + i * 2 + 1];
        float fbv;
        {
            float tmp[4];
            load4(g_coset, ((b * NN + n1) * SS + ps1) * CIN, fmode, tmp);
            fbv = tmp[i];
        }
        float fnew = fbv + num / den;
        int m1 = load_mask(g_mask, (b * NN + n1) * SS + ps1, mmode);
        sm[O_CF + ps1 * 4 + i] = m1 ? fnew : 0.f;
    }
    __syncthreads();
    if (tid < 32) {
        const int ps1 = tid >> 3, o = tid & 7;
        float v = 0.f;
#pragma unroll
        for (int i = 0; i < CIN; ++i)
            v += sm[O_CF + ps1 * 4 + i] * sm[O_WOUT + o * 4 + i];
        const int oidx = ((b * NN + n1) * SS + ps1) * COUT + o;
        if (fmode) ((__hip_bfloat16*)outp)[oidx] = __float2bfloat16(v);
        else       ((float*)outp)[oidx] = v;
    }
}

extern "C" void kernel_launch(void* const* d_in, const int* in_sizes, int n_in,
                              void* d_out, int out_size, void* d_ws, size_t ws_size,
                              hipStream_t stream) {
    int* modes = (int*)d_ws;  // re-written every call (ws is re-poisoned)
    detect_kernel<<<1, 64, 0, stream>>>(d_in[2], d_in[1], modes);
    emha_kernel<<<BB * NN, 512, 0, stream>>>(
        d_in[0], d_in[1], d_in[2],
        d_in[3], d_in[4], d_in[5], d_in[6], d_in[7], d_in[8],
        d_in[9], d_in[10], d_in[11], d_in[12], d_in[13], d_in[14],
        d_in[15], modes, d_out);
}

// Round 2
// 247.781 us; speedup vs baseline: 2.6588x; 2.6588x over previous
//
#include <hip/hip_runtime.h>
#include <hip/hip_bf16.h>

#define BB   2
#define NN   128
#define SS   4
#define DGG  8
#define CIN  4
#define COUT 8
#define HH   32

typedef __attribute__((ext_vector_type(4))) float          fvec4;
typedef __attribute__((ext_vector_type(4))) unsigned short usvec4;
typedef __attribute__((ext_vector_type(8))) unsigned short usvec8;

// LDS layout (float offsets)
#define O_YW1  0      // ky_W1: 4*32*2   = 256
#define O_YB1  256    // ky_b1: 4*32     = 128
#define O_YW2  384    // ky_W2: 4*32*32  = 4096
#define O_YB2  4480   // ky_b2: 128
#define O_YW3  4608   // ky_W3: 128
#define O_YB3  4736   // ky_b3: 4
#define O_GW1  4740   // kg_W1: 4*32*8   = 1024
#define O_GB1  5764   // kg_b1: 128
#define O_GW2  5892   // kg_W2: 4096
#define O_GB2  9988   // kg_b2: 128
#define O_GW3  10116  // kg_W3: 128
#define O_GB3  10244  // kg_b3: 4
#define O_WOUT 10248  // w_out: 32
#define W_TOTAL 10280
#define O_PART  W_TOTAL          // 8 waves * 4 s1 * 8 = 256
#define O_ACCF  (W_TOTAL + 256)  // 32
#define O_CF    (W_TOTAL + 288)  // 16
#define SM_TOTAL (W_TOTAL + 304)

__device__ __forceinline__ float bf2f(unsigned short u) {
    return __uint_as_float(((unsigned int)u) << 16);
}

__device__ __forceinline__ float silu_f(float x) {
    return x * __builtin_amdgcn_rcpf(1.0f + __expf(-x));
}

// ---- dtype detection (deterministic, graph-capture safe) ----
// modes[0]: 0 = float tensors are f32, 1 = bf16
// modes[1]: mask dtype: 0=i32, 1=bf16, 2=u8/bool, 3=f32
__global__ void detect_kernel(const void* maskp, const void* cosetp, int* modes) {
    int lane = threadIdx.x;  // 64 threads
    const unsigned short* cu = (const unsigned short*)cosetp;
    unsigned short v = cu[2 * lane];
    int e = (v >> 7) & 0xFF;
    int hit = (e >= 110 && e <= 135) ? 1 : 0;
    int hits = __popcll(__ballot(hit));
    int fmode = (hits > 32) ? 1 : 0;

    const unsigned short* mu = (const unsigned short*)maskp;
    int evenBF = 0, any3 = 0, anyByte = 0;
    for (int r = 0; r < 8; ++r) {
        int idx = lane + r * 64;
        unsigned short m = mu[idx];
        if (m == 0x3F80) { any3 = 1; if (!(idx & 1)) evenBF = 1; }
        if (m == 0x0101 || m == 0x0100) anyByte = 1;
    }
    evenBF  = (__ballot(evenBF)  != 0ull);
    any3    = (__ballot(any3)    != 0ull);
    anyByte = (__ballot(anyByte) != 0ull);
    if (lane == 0) {
        modes[0] = fmode;
        modes[1] = evenBF ? 1 : (any3 ? 3 : (anyByte ? 2 : 0));
    }
}

__device__ __forceinline__ void copy_arr(float* sm, const void* src, int off,
                                         int cnt, int fmode, int tid) {
    if (fmode) {
        const unsigned short* s = (const unsigned short*)src;
        for (int x = tid; x < cnt; x += 512) sm[off + x] = bf2f(s[x]);
    } else {
        const float* s = (const float*)src;
        for (int x = tid; x < cnt; x += 512) sm[off + x] = s[x];
    }
}

__device__ __forceinline__ void load4(const void* p, int base, int fmode, float* dst) {
    if (fmode) {
        usvec4 v = *(const usvec4*)((const unsigned short*)p + base);
        dst[0] = bf2f(v[0]); dst[1] = bf2f(v[1]);
        dst[2] = bf2f(v[2]); dst[3] = bf2f(v[3]);
    } else {
        fvec4 v = *(const fvec4*)((const float*)p + base);
        dst[0] = v[0]; dst[1] = v[1]; dst[2] = v[2]; dst[3] = v[3];
    }
}

__device__ __forceinline__ void load8(const void* p, int base, int fmode, float* dst) {
    if (fmode) {
        usvec8 v = *(const usvec8*)((const unsigned short*)p + base);
#pragma unroll
        for (int d = 0; d < 8; ++d) dst[d] = bf2f(v[d]);
    } else {
        fvec4 a = *(const fvec4*)((const float*)p + base);
        fvec4 b = *(const fvec4*)((const float*)p + base + 4);
        dst[0] = a[0]; dst[1] = a[1]; dst[2] = a[2]; dst[3] = a[3];
        dst[4] = b[0]; dst[5] = b[1]; dst[6] = b[2]; dst[7] = b[3];
    }
}

__device__ __forceinline__ int load_mask(const void* p, int idx, int mmode) {
    if (mmode == 0) return ((const int*)p)[idx] != 0;
    if (mmode == 1) return ((const unsigned short*)p)[idx] != 0;
    if (mmode == 2) return ((const unsigned char*)p)[idx] != 0;
    return ((const unsigned int*)p)[idx] != 0;
}

// One block per (b, n1). 512 threads: t = n2b*16 + s1*4 + s2, n2b in [0,32).
// Each thread covers all 4 n2 = n2b + p*32 (P=4 position batching: each
// ds_read_b128 of weights feeds 16 FMAs).  ALL per-thread-array indices are
// compile-time constants (full unroll) so h1 stays in VGPRs — the round-1
// scratch-spill (1.6 GB WRITE_SIZE) came from partially-unrolled j-loops.
// Layer 2 is fused with layer 3 so h2 never materializes.
__global__ __launch_bounds__(512, 2) void emha_kernel(
    const void* __restrict__ g_pw, const void* __restrict__ g_coset,
    const void* __restrict__ g_mask,
    const void* yW1, const void* yb1, const void* yW2, const void* yb2,
    const void* yW3, const void* yb3,
    const void* gW1, const void* gb1, const void* gW2, const void* gb2,
    const void* gW3, const void* gb3,
    const void* wout, const int* modes, void* outp)
{
    __shared__ float sm[SM_TOTAL];
    const int tid = threadIdx.x;
    const int fmode = modes[0];
    const int mmode = modes[1];
    const int blk = blockIdx.x;
    const int b  = blk >> 7;
    const int n1 = blk & 127;

    copy_arr(sm, yW1, O_YW1, 256,  fmode, tid);
    copy_arr(sm, yb1, O_YB1, 128,  fmode, tid);
    copy_arr(sm, yW2, O_YW2, 4096, fmode, tid);
    copy_arr(sm, yb2, O_YB2, 128,  fmode, tid);
    copy_arr(sm, yW3, O_YW3, 128,  fmode, tid);
    copy_arr(sm, yb3, O_YB3, 4,    fmode, tid);
    copy_arr(sm, gW1, O_GW1, 1024, fmode, tid);
    copy_arr(sm, gb1, O_GB1, 128,  fmode, tid);
    copy_arr(sm, gW2, O_GW2, 4096, fmode, tid);
    copy_arr(sm, gb2, O_GB2, 128,  fmode, tid);
    copy_arr(sm, gW3, O_GW3, 128,  fmode, tid);
    copy_arr(sm, gb3, O_GB3, 4,    fmode, tid);
    copy_arr(sm, wout, O_WOUT, 32, fmode, tid);
    __syncthreads();

    const int s2  = tid & 3;
    const int s1  = (tid >> 2) & 3;
    const int n2b = tid >> 4;

    float fb[4];
    load4(g_coset, ((b * NN + n1) * SS + s1) * CIN, fmode, fb);

    float fa[4][4];
    float gv[4][8];
    int   mbits = 0;
#pragma unroll
    for (int p = 0; p < 4; ++p) {
        const int n2 = n2b + p * 32;
        const int pos = (((b * NN + n1) * NN + n2) * SS + s1) * SS + s2;
        load8(g_pw, pos * DGG, fmode, gv[p]);
        load4(g_coset, ((b * NN + n2) * SS + s2) * CIN, fmode, fa[p]);
        mbits |= load_mask(g_mask, (b * NN + n2) * SS + s2, mmode) << p;
    }

    float accN[4] = {0.f, 0.f, 0.f, 0.f};
    float accD[4] = {0.f, 0.f, 0.f, 0.f};

#pragma unroll
    for (int i = 0; i < CIN; ++i) {
        float h1[4][HH];
        // ---- ky layer 1 (fully unrolled: writes h1[p][j]) ----
        {
            const float* W1 = &sm[O_YW1 + i * 64];
            const float* B1 = &sm[O_YB1 + i * HH];
#pragma unroll
            for (int j = 0; j < HH; ++j) {
                float w0 = W1[2 * j], w1 = W1[2 * j + 1];
                float c = w1 * fb[i] + B1[j];
#pragma unroll
                for (int p = 0; p < 4; ++p)
                    h1[p][j] = silu_f(w0 * fa[p][i] + c);
            }
        }
        // ---- ky layers 2+3 fused (h2 never materializes) ----
        float kyv[4];
        {
            const float* W2 = &sm[O_YW2 + i * 1024];
            const float* B2 = &sm[O_YB2 + i * HH];
            const float* W3 = &sm[O_YW3 + i * HH];
            float a3[4] = {0.f, 0.f, 0.f, 0.f};
#pragma unroll 2
            for (int j = 0; j < HH; ++j) {
                float d[4] = {0.f, 0.f, 0.f, 0.f};
#pragma unroll
                for (int k = 0; k < HH; ++k) {
                    float w = W2[j * HH + k];
#pragma unroll
                    for (int p = 0; p < 4; ++p) d[p] += w * h1[p][k];
                }
                float bb = B2[j], w3 = W3[j];
#pragma unroll
                for (int p = 0; p < 4; ++p) a3[p] += w3 * silu_f(d[p] + bb);
            }
            float b3 = sm[O_YB3 + i];
#pragma unroll
            for (int p = 0; p < 4; ++p) kyv[p] = silu_f(a3[p] + b3);
        }
        // ---- kg layer 1 (fully unrolled: writes h1[p][j]) ----
        {
            const float* W1 = &sm[O_GW1 + i * 256];
            const float* B1 = &sm[O_GB1 + i * HH];
#pragma unroll
            for (int j = 0; j < HH; ++j) {
                float bb = B1[j];
                float d[4] = {bb, bb, bb, bb};
#pragma unroll
                for (int d8 = 0; d8 < DGG; ++d8) {
                    float w = W1[j * DGG + d8];
#pragma unroll
                    for (int p = 0; p < 4; ++p) d[p] += w * gv[p][d8];
                }
#pragma unroll
                for (int p = 0; p < 4; ++p) h1[p][j] = silu_f(d[p]);
            }
        }
        // ---- kg layers 2+3 fused ----
        float kgv[4];
        {
            const float* W2 = &sm[O_GW2 + i * 1024];
            const float* B2 = &sm[O_GB2 + i * HH];
            const float* W3 = &sm[O_GW3 + i * HH];
            float a3[4] = {0.f, 0.f, 0.f, 0.f};
#pragma unroll 2
            for (int j = 0; j < HH; ++j) {
                float d[4] = {0.f, 0.f, 0.f, 0.f};
#pragma unroll
                for (int k = 0; k < HH; ++k) {
                    float w = W2[j * HH + k];
#pragma unroll
                    for (int p = 0; p < 4; ++p) d[p] += w * h1[p][k];
                }
                float bb = B2[j], w3 = W3[j];
#pragma unroll
                for (int p = 0; p < 4; ++p) a3[p] += w3 * silu_f(d[p] + bb);
            }
            float b3 = sm[O_GB3 + i];
#pragma unroll
            for (int p = 0; p < 4; ++p) kgv[p] = silu_f(a3[p] + b3);
        }
        // ---- combine: masked exp, accumulate numerator/denominator ----
#pragma unroll
        for (int p = 0; p < 4; ++p) {
            float e = ((mbits >> p) & 1) ? __expf(kyv[p] + kgv[p]) : 0.f;
            accD[i] += e;
            accN[i] += e * fa[p][i];
        }
    }

    // Reduce over s2 (lane bits 0,1) and n2b-low (lane bits 4,5)
#pragma unroll
    for (int i = 0; i < CIN; ++i) {
        accN[i] += __shfl_xor(accN[i], 1);
        accD[i] += __shfl_xor(accD[i], 1);
        accN[i] += __shfl_xor(accN[i], 2);
        accD[i] += __shfl_xor(accD[i], 2);
        accN[i] += __shfl_xor(accN[i], 16);
        accD[i] += __shfl_xor(accD[i], 16);
        accN[i] += __shfl_xor(accN[i], 32);
        accD[i] += __shfl_xor(accD[i], 32);
    }
    const int lane = tid & 63;
    const int wave = tid >> 6;
    if ((lane & 51) == 0) {  // lanes 0,4,8,12: holders per s1
        const int ps1 = (lane >> 2) & 3;
        float* p = &sm[O_PART + (wave * 4 + ps1) * 8];
#pragma unroll
        for (int i = 0; i < CIN; ++i) {
            p[i * 2]     = accN[i];
            p[i * 2 + 1] = accD[i];
        }
    }
    __syncthreads();
    if (tid < 32) {
        const int ps1 = tid >> 3, j = tid & 7;
        float v = 0.f;
#pragma unroll
        for (int w = 0; w < 8; ++w) v += sm[O_PART + (w * 4 + ps1) * 8 + j];
        sm[O_ACCF + ps1 * 8 + j] = v;
    }
    __syncthreads();
    if (tid < 16) {
        const int ps1 = tid >> 2, i = tid & 3;
        float num = sm[O_ACCF + ps1 * 8 + i * 2];
        float den = sm[O_ACCF + ps1 * 8 + i * 2 + 1];
        float fbv;
        {
            float tmp[4];
            load4(g_coset, ((b * NN + n1) * SS + ps1) * CIN, fmode, tmp);
            fbv = tmp[i];
        }
        float fnew = fbv + num / den;
        int m1 = load_mask(g_mask, (b * NN + n1) * SS + ps1, mmode);
        sm[O_CF + ps1 * 4 + i] = m1 ? fnew : 0.f;
    }
    __syncthreads();
    if (tid < 32) {
        const int ps1 = tid >> 3, o = tid & 7;
        float v = 0.f;
#pragma unroll
        for (int i = 0; i < CIN; ++i)
            v += sm[O_CF + ps1 * 4 + i] * sm[O_WOUT + o * 4 + i];
        const int oidx = ((b * NN + n1) * SS + ps1) * COUT + o;
        if (fmode) ((__hip_bfloat16*)outp)[oidx] = __float2bfloat16(v);
        else       ((float*)outp)[oidx] = v;
    }
}

extern "C" void kernel_launch(void* const* d_in, const int* in_sizes, int n_in,
                              void* d_out, int out_size, void* d_ws, size_t ws_size,
                              hipStream_t stream) {
    int* modes = (int*)d_ws;  // re-written every call (ws is re-poisoned)
    detect_kernel<<<1, 64, 0, stream>>>(d_in[2], d_in[1], modes);
    emha_kernel<<<BB * NN, 512, 0, stream>>>(
        d_in[0], d_in[1], d_in[2],
        d_in[3], d_in[4], d_in[5], d_in[6], d_in[7], d_in[8],
        d_in[9], d_in[10], d_in[11], d_in[12], d_in[13], d_in[14],
        d_in[15], modes, d_out);
}